// Round 2
// baseline (434.458 us; speedup 1.0000x reference)
//
#include <hip/hip_runtime.h>

#define NFFT 1024
#define TWO_PI 6.28318530717958647692f

// XOR bank swizzle: flips addr bits [4:2] with a hash of bits [7:5]^[10:8].
// Preserves low 2 bits -> 4-float groups stay contiguous & 16B-aligned (b128 ok).
__device__ __forceinline__ int SW(int a) {
    return a ^ ((((a >> 5) ^ (a >> 8)) & 7) << 2);
}

// Inverse radix-4 butterfly (uses +i): u0=t0+t1+t2+t3; u1=(t0-t2)+i(t1-t3);
// u2=t0-t1+t2-t3; u3=(t0-t2)-i(t1-t3)
__device__ __forceinline__ void bfly4(float& r0, float& i0, float& r1, float& i1,
                                      float& r2, float& i2, float& r3, float& i3) {
    float d0r = r0 + r2, d0i = i0 + i2;
    float d1r = r0 - r2, d1i = i0 - i2;
    float d2r = r1 + r3, d2i = i1 + i3;
    float sr  = r1 - r3, si  = i1 - i3;
    r0 = d0r + d2r; i0 = d0i + d2i;
    r2 = d0r - d2r; i2 = d0i - d2i;
    r1 = d1r - si;  i1 = d1i + sr;   // u1 = d1 + i*s
    r3 = d1r + si;  i3 = d1i - sr;   // u3 = d1 - i*s
}

__device__ __forceinline__ void twmul(float& x, float& y, float c, float s) {
    float t = x * c - y * s;
    y = x * s + y * c;
    x = t;
}

// One 1024-pt inverse FFT per 64-thread block. 16 complex points per thread.
// In-place DIF radix-4, 5 stages; stages (0,1),(2,3),(4) in registers,
// two LDS exchanges between them. Digit reversal folded into global I/O.
__global__ __launch_bounds__(64, 4) void ifft1024_kernel(
        const float* __restrict__ re, const float* __restrict__ im,
        float* __restrict__ out, size_t imoff) {
    __shared__ __align__(16) float lds[2048];   // re:[0,1024) im:[1024,2048)
    const int u = threadIdx.x;
    const size_t rowb = (size_t)blockIdx.x * NFFT;

    float vr[4][4], vi[4][4];

    // Load: v[a][b] = x[u + 64a + 256b]  (each instr: dense 256B segment)
#pragma unroll
    for (int b = 0; b < 4; ++b)
#pragma unroll
        for (int a = 0; a < 4; ++a) {
            int idx = u + 64 * a + 256 * b;
            vr[a][b] = re[rowb + idx];
            vi[a][b] = im[rowb + idx];
        }

    // ---- stage 0: B=1024, legs over b (stride 256), twiddle W1024^{(u+64a)q}
#pragma unroll
    for (int a = 0; a < 4; ++a) {
        bfly4(vr[a][0], vi[a][0], vr[a][1], vi[a][1],
              vr[a][2], vi[a][2], vr[a][3], vi[a][3]);
        float ang = (TWO_PI / 1024.f) * (float)(u + 64 * a);
        float s1, c1; __sincosf(ang, &s1, &c1);
        float c2 = c1 * c1 - s1 * s1, s2 = 2.f * c1 * s1;
        float c3 = c2 * c1 - s2 * s1, s3 = c2 * s1 + s2 * c1;
        twmul(vr[a][1], vi[a][1], c1, s1);
        twmul(vr[a][2], vi[a][2], c2, s2);
        twmul(vr[a][3], vi[a][3], c3, s3);
    }

    // ---- stage 1: B=256, legs over a (stride 64), twiddle W256^{u q}
    {
        float ang = (TWO_PI / 256.f) * (float)u;
        float s1, c1; __sincosf(ang, &s1, &c1);
        float c2 = c1 * c1 - s1 * s1, s2 = 2.f * c1 * s1;
        float c3 = c2 * c1 - s2 * s1, s3 = c2 * s1 + s2 * c1;
#pragma unroll
        for (int b = 0; b < 4; ++b) {
            bfly4(vr[0][b], vi[0][b], vr[1][b], vi[1][b],
                  vr[2][b], vi[2][b], vr[3][b], vi[3][b]);
            twmul(vr[1][b], vi[1][b], c1, s1);
            twmul(vr[2][b], vi[2][b], c2, s2);
            twmul(vr[3][b], vi[3][b], c3, s3);
        }
    }

    // ---- exchange A: layout qA(p) = a + 4b + 16*(p%64)  [p = u + 64a + 256b]
    // write: 4x b128 at 16u+4b holding (v[0..3][b])
#pragma unroll
    for (int b = 0; b < 4; ++b) {
        *(float4*)&lds[SW(16 * u + 4 * b)] =
            make_float4(vr[0][b], vr[1][b], vr[2][b], vr[3][b]);
        *(float4*)&lds[SW(16 * u + 4 * b + 1024)] =
            make_float4(vi[0][b], vi[1][b], vi[2][b], vi[3][b]);
    }
    __syncthreads();
    // read: new ownership p' = (u&3) + 4a + 16b + 64*(u>>2)
    // qA(p') = (u>>2) + 16*(u&3) + 64a + 256b
    {
        int lo = (u >> 2) + 16 * (u & 3);
#pragma unroll
        for (int b = 0; b < 4; ++b)
#pragma unroll
            for (int a = 0; a < 4; ++a) {
                int q = lo + 64 * a + 256 * b;
                vr[a][b] = lds[SW(q)];
                vi[a][b] = lds[SW(q + 1024)];
            }
    }

    // ---- stage 2: B=64, legs over b (stride 16), twiddle W64^{(w+4a)q}, w=u&3
    const int w = u & 3;
#pragma unroll
    for (int a = 0; a < 4; ++a) {
        bfly4(vr[a][0], vi[a][0], vr[a][1], vi[a][1],
              vr[a][2], vi[a][2], vr[a][3], vi[a][3]);
        float ang = (TWO_PI / 64.f) * (float)(w + 4 * a);
        float s1, c1; __sincosf(ang, &s1, &c1);
        float c2 = c1 * c1 - s1 * s1, s2 = 2.f * c1 * s1;
        float c3 = c2 * c1 - s2 * s1, s3 = c2 * s1 + s2 * c1;
        twmul(vr[a][1], vi[a][1], c1, s1);
        twmul(vr[a][2], vi[a][2], c2, s2);
        twmul(vr[a][3], vi[a][3], c3, s3);
    }

    // ---- stage 3: B=16, legs over a (stride 4), twiddle W16^{w q}
    {
        float ang = (TWO_PI / 16.f) * (float)w;
        float s1, c1; __sincosf(ang, &s1, &c1);
        float c2 = c1 * c1 - s1 * s1, s2 = 2.f * c1 * s1;
        float c3 = c2 * c1 - s2 * s1, s3 = c2 * s1 + s2 * c1;
#pragma unroll
        for (int b = 0; b < 4; ++b) {
            bfly4(vr[0][b], vi[0][b], vr[1][b], vi[1][b],
                  vr[2][b], vi[2][b], vr[3][b], vi[3][b]);
            twmul(vr[1][b], vi[1][b], c1, s1);
            twmul(vr[2][b], vi[2][b], c2, s2);
            twmul(vr[3][b], vi[3][b], c3, s3);
        }
    }
    __syncthreads();   // protect LDS reuse (all exchange-A reads done)

    // ---- exchange B: layout qB(p) = b + 4a + 16*(p&3) + 64*(p>>6)... = b+4a+16u here
    // write: 4x b128 at 16u+4a holding (v[a][0..3])
#pragma unroll
    for (int a = 0; a < 4; ++a) {
        *(float4*)&lds[SW(16 * u + 4 * a)] =
            make_float4(vr[a][0], vr[a][1], vr[a][2], vr[a][3]);
        *(float4*)&lds[SW(16 * u + 4 * a + 1024)] =
            make_float4(vi[a][0], vi[a][1], vi[a][2], vi[a][3]);
    }
    __syncthreads();
    // read: new ownership p = 16u + 4c + e  ->  qB = (u&3) + 4c + 16e + 64*(u>>2)
    {
        int lo = (u & 3) + 64 * (u >> 2);
#pragma unroll
        for (int c = 0; c < 4; ++c)
#pragma unroll
            for (int e = 0; e < 4; ++e) {
                int q = lo + 4 * c + 16 * e;
                vr[c][e] = lds[SW(q)];
                vi[c][e] = lds[SW(q + 1024)];
            }
    }

    // ---- stage 4: B=4, legs over e (stride 1), no twiddle
#pragma unroll
    for (int c = 0; c < 4; ++c)
        bfly4(vr[c][0], vi[c][0], vr[c][1], vi[c][1],
              vr[c][2], vi[c][2], vr[c][3], vi[c][3]);

    // ---- output: position p = 16u+4c+e holds y[rev4(p)];
    // n = 256e + 64c + 16(u&3) + 4((u>>2)&3) + (u>>4). Per (c,e): one permuted
    // 256B segment across lanes -> fully coalesced.
    const float sc = 1.f / 1024.f;
    const int nbase = 16 * (u & 3) + 4 * ((u >> 2) & 3) + (u >> 4);
#pragma unroll
    for (int e = 0; e < 4; ++e)
#pragma unroll
        for (int c = 0; c < 4; ++c) {
            int n = nbase + 64 * c + 256 * e;
            out[rowb + n]         = vr[c][e] * sc;
            out[imoff + rowb + n] = vi[c][e] * sc;
        }
}

extern "C" void kernel_launch(void* const* d_in, const int* in_sizes, int n_in,
                              void* d_out, int out_size, void* d_ws, size_t ws_size,
                              hipStream_t stream) {
    const float* re = (const float*)d_in[0];
    const float* im = (const float*)d_in[1];
    float* out = (float*)d_out;
    const int rows = in_sizes[0] / NFFT;          // 32768
    const size_t im_off = (size_t)in_sizes[0];    // output: [re | im] flat

    hipLaunchKernelGGL(ifft1024_kernel, dim3(rows), dim3(64), 0, stream,
                       re, im, out, im_off);
}

// Round 3
// 433.204 us; speedup vs baseline: 1.0029x; 1.0029x over previous
//
#include <hip/hip_runtime.h>

#define NFFT 1024
#define TWO_PI 6.28318530717958647692f

// Inverse radix-4 butterfly (+i convention), verified in round 1.
__device__ __forceinline__ void bfly4(float& r0, float& i0, float& r1, float& i1,
                                      float& r2, float& i2, float& r3, float& i3) {
    float d0r = r0 + r2, d0i = i0 + i2;
    float d1r = r0 - r2, d1i = i0 - i2;
    float d2r = r1 + r3, d2i = i1 + i3;
    float sr  = r1 - r3, si  = i1 - i3;
    r0 = d0r + d2r; i0 = d0i + d2i;
    r2 = d0r - d2r; i2 = d0i - d2i;
    r1 = d1r - si;  i1 = d1i + sr;   // u1 = d1 + i*s
    r3 = d1r + si;  i3 = d1i - sr;   // u3 = d1 - i*s
}

__device__ __forceinline__ void twmul(float& x, float& y, float c, float s) {
    float t = x * c - y * s;
    y = x * s + y * c;
    x = t;
}

// One row per WAVE (4 rows / 256-thread block), wave-private 8KB LDS slice,
// no s_barrier. Stages: S0 | exchA | S1,S2 | exchB | S3,S4.
// Swizzle: flip addr bit4 by addr bit8 -> all LDS patterns <=2-way (free).
__global__ __launch_bounds__(256, 4) void ifft1024_kernel(
        const float* __restrict__ re, const float* __restrict__ im,
        float* __restrict__ out, size_t imoff) {
    __shared__ __align__(16) float lds_all[8192];   // 4 waves x 2048 floats
    const int tid = threadIdx.x;
    const int u   = tid & 63;
    const int wv  = tid >> 6;
    float* lds = lds_all + (wv << 11);              // re:[0,1024) im:[1024,2048)

    const size_t row  = (size_t)blockIdx.x * 4 + wv;
    const size_t rowb = row * NFFT;

    // ---- load: p = 4u + k + 256b  ->  v[k][b], float4 per b (1KB/wave-instr)
    float vr[4][4], vi[4][4];
#pragma unroll
    for (int b = 0; b < 4; ++b) {
        float4 r4 = *(const float4*)(re + rowb + 4 * u + 256 * b);
        float4 i4 = *(const float4*)(im + rowb + 4 * u + 256 * b);
        vr[0][b] = r4.x; vr[1][b] = r4.y; vr[2][b] = r4.z; vr[3][b] = r4.w;
        vi[0][b] = i4.x; vi[1][b] = i4.y; vi[2][b] = i4.z; vi[3][b] = i4.w;
    }

    // ---- S0: B=1024, legs over b (stride 256), twiddle W1024^{(4u+k)q}
    {
        float c1, s1;
        __sincosf((TWO_PI / 256.f) * (float)u, &s1, &c1);     // angle of 4u
        const float CS = 0.9999811752826011f;                 // cos(2pi/1024)
        const float SN = 0.0061358846491544753f;              // sin(2pi/1024)
#pragma unroll
        for (int k = 0; k < 4; ++k) {
            bfly4(vr[k][0], vi[k][0], vr[k][1], vi[k][1],
                  vr[k][2], vi[k][2], vr[k][3], vi[k][3]);
            float c2 = c1 * c1 - s1 * s1, s2 = 2.f * c1 * s1;
            float c3 = c2 * c1 - s2 * s1, s3 = c2 * s1 + s2 * c1;
            twmul(vr[k][1], vi[k][1], c1, s1);
            twmul(vr[k][2], vi[k][2], c2, s2);
            twmul(vr[k][3], vi[k][3], c3, s3);
            float nc = c1 * CS - s1 * SN, ns = c1 * SN + s1 * CS;
            c1 = nc; s1 = ns;                                  // rotate to 4u+k+1
        }
    }

    // ---- exchange A: write p=4u+k+256b (b128), read p=j+16a+64c+256h
    // swizzled addr: bit8(p)=b&1 (write) / h&1 (read); no carries in sums.
#pragma unroll
    for (int b = 0; b < 4; ++b) {
        int q = (4 * u + 256 * b) ^ ((b & 1) << 4);
        *(float4*)&lds[q]        = make_float4(vr[0][b], vr[1][b], vr[2][b], vr[3][b]);
        *(float4*)&lds[q + 1024] = make_float4(vi[0][b], vi[1][b], vi[2][b], vi[3][b]);
    }
    __threadfence_block();   // order within wave; slices are wave-private

    const int j = u & 15, h = u >> 4;
    const int flip = (h & 1) << 4;
    float wr[4][4], wi[4][4];   // [a][c]
    {
        const int rb = j + 256 * h;
#pragma unroll
        for (int a = 0; a < 4; ++a)
#pragma unroll
            for (int c = 0; c < 4; ++c) {
                int q = rb + ((16 * a) ^ flip) + 64 * c;   // == SWZ(j+16a+64c+256h)
                wr[a][c] = lds[q];
                wi[a][c] = lds[q + 1024];
            }
    }

    // ---- S1: B=256, legs over c (stride 64), twiddle W256^{(j+16a)q}
    {
        float cA, sA;
        __sincosf((TWO_PI / 256.f) * (float)j, &sA, &cA);
        const float CS8 = 0.9238795325112867f;   // cos(pi/8): step for a+=1
        const float SN8 = 0.3826834323650898f;
#pragma unroll
        for (int a = 0; a < 4; ++a) {
            bfly4(wr[a][0], wi[a][0], wr[a][1], wi[a][1],
                  wr[a][2], wi[a][2], wr[a][3], wi[a][3]);
            float c2 = cA * cA - sA * sA, s2 = 2.f * cA * sA;
            float c3 = c2 * cA - s2 * sA, s3 = c2 * sA + s2 * cA;
            twmul(wr[a][1], wi[a][1], cA, sA);
            twmul(wr[a][2], wi[a][2], c2, s2);
            twmul(wr[a][3], wi[a][3], c3, s3);
            float nc = cA * CS8 - sA * SN8, ns = cA * SN8 + sA * CS8;
            cA = nc; sA = ns;
        }
    }

    // ---- S2: B=64, legs over a (stride 16), twiddle W64^{j q}
    {
        float cB, sB;
        __sincosf((TWO_PI / 64.f) * (float)j, &sB, &cB);
        float cB2 = cB * cB - sB * sB, sB2 = 2.f * cB * sB;
        float cB3 = cB2 * cB - sB2 * sB, sB3 = cB2 * sB + sB2 * cB;
#pragma unroll
        for (int c = 0; c < 4; ++c) {
            bfly4(wr[0][c], wi[0][c], wr[1][c], wi[1][c],
                  wr[2][c], wi[2][c], wr[3][c], wi[3][c]);
            twmul(wr[1][c], wi[1][c], cB, sB);
            twmul(wr[2][c], wi[2][c], cB2, sB2);
            twmul(wr[3][c], wi[3][c], cB3, sB3);
        }
    }

    // ---- exchange B: write p=j+16a+64c+256h (b32), read p=16u+4e+f (b128)
    __threadfence_block();   // all exchA reads done before overwrite
    {
        const int rb = j + 256 * h;
#pragma unroll
        for (int a = 0; a < 4; ++a)
#pragma unroll
            for (int c = 0; c < 4; ++c) {
                int q = rb + ((16 * a) ^ flip) + 64 * c;
                lds[q]        = wr[a][c];
                lds[q + 1024] = wi[a][c];
            }
    }
    __threadfence_block();

    float yr[4][4], yi[4][4];   // [e][f]
    {
        const int rb = (16 * u) ^ flip;   // bit8(16u) = h&1
#pragma unroll
        for (int e = 0; e < 4; ++e) {
            float4 r4 = *(const float4*)&lds[rb + 4 * e];
            float4 i4 = *(const float4*)&lds[rb + 4 * e + 1024];
            yr[e][0] = r4.x; yr[e][1] = r4.y; yr[e][2] = r4.z; yr[e][3] = r4.w;
            yi[e][0] = i4.x; yi[e][1] = i4.y; yi[e][2] = i4.z; yi[e][3] = i4.w;
        }
    }

    // ---- S3: B=16, legs over e (stride 4), twiddle W16^{f q} (constants)
#pragma unroll
    for (int f = 0; f < 4; ++f)
        bfly4(yr[0][f], yi[0][f], yr[1][f], yi[1][f],
              yr[2][f], yi[2][f], yr[3][f], yi[3][f]);
    {
        const float C1 = 0.9238795325112867f,  S1 = 0.3826834323650898f;   // W16^1
        const float C2 = 0.7071067811865476f,  S2 = 0.7071067811865476f;   // W16^2
        const float C3 = 0.3826834323650898f,  S3 = 0.9238795325112867f;   // W16^3
        const float C6 = -0.7071067811865476f, S6 = 0.7071067811865476f;   // W16^6
        const float C9 = -0.9238795325112867f, S9 = -0.3826834323650898f;  // W16^9
        twmul(yr[1][1], yi[1][1], C1, S1);
        twmul(yr[2][1], yi[2][1], C2, S2);
        twmul(yr[3][1], yi[3][1], C3, S3);
        twmul(yr[1][2], yi[1][2], C2, S2);
        twmul(yr[2][2], yi[2][2], 0.f, 1.f);   // *i
        twmul(yr[3][2], yi[3][2], C6, S6);
        twmul(yr[1][3], yi[1][3], C3, S3);
        twmul(yr[2][3], yi[2][3], C6, S6);
        twmul(yr[3][3], yi[3][3], C9, S9);
    }

    // ---- S4: B=4, legs over f (stride 1), no twiddle
#pragma unroll
    for (int e = 0; e < 4; ++e)
        bfly4(yr[e][0], yi[e][0], yr[e][1], yi[e][1],
              yr[e][2], yi[e][2], yr[e][3], yi[e][3]);

    // ---- store: p = 16u+4e+f holds X[rev4(p)];
    // n = 256f + 64e + 16(u&3) + 4((u>>2)&3) + (u>>4)  (round-1-verified)
    const float sc = 1.f / 1024.f;
    const int nb = 16 * (u & 3) + 4 * ((u >> 2) & 3) + (u >> 4);
#pragma unroll
    for (int f = 0; f < 4; ++f)
#pragma unroll
        for (int e = 0; e < 4; ++e) {
            int n = nb + 64 * e + 256 * f;
            out[rowb + n]         = yr[e][f] * sc;
            out[imoff + rowb + n] = yi[e][f] * sc;
        }
}

extern "C" void kernel_launch(void* const* d_in, const int* in_sizes, int n_in,
                              void* d_out, int out_size, void* d_ws, size_t ws_size,
                              hipStream_t stream) {
    const float* re = (const float*)d_in[0];
    const float* im = (const float*)d_in[1];
    float* out = (float*)d_out;
    const int rows = in_sizes[0] / NFFT;          // 32768
    const size_t im_off = (size_t)in_sizes[0];    // output: [re | im] flat

    hipLaunchKernelGGL(ifft1024_kernel, dim3(rows / 4), dim3(256), 0, stream,
                       re, im, out, im_off);
}